// Round 1
// 663.745 us; speedup vs baseline: 1.0251x; 1.0251x over previous
//
#include <hip/hip_runtime.h>
#include <hip/hip_bf16.h>
#include <math.h>

// Problem constants: MUL=128, LS=0..4, DIM=3200, N=16384
// gathered layout: m-blocks width C[m]={640,1024,768,512,256}, offsets {0,640,1664,2432,2944}
#define N_ROWS 16384
#define DIM    3200

using short8  = __attribute__((ext_vector_type(8))) short;
using floatx4 = __attribute__((ext_vector_type(4))) float;

__device__ const int c_K [5] = {640, 1024, 768, 512, 256};
__device__ const int c_UO[5] = {0, 640, 1664, 2432, 2944};
__device__ const int c_WO[5] = {0, 409600, 1458176, 2048000, 2310144};
// 13 column tiles of width 256 across the 5 m-blocks (m0 ragged: 640 = 2.5 tiles, clamped)
__device__ const int c_m13 [13] = {0,0,0, 1,1,1,1, 2,2,2, 3,3, 4};
__device__ const int c_nt13[13] = {0,1,2, 0,1,2,3, 0,1,2, 0,1, 0};

__device__ __forceinline__ constexpr int joff_of(int l) { return l==1 ? 0 : l==2 ? 9 : l==3 ? 34 : 83; }
__device__ __forceinline__ constexpr int gO(int m)      { return m==1 ? 640 : m==2 ? 1664 : m==3 ? 2432 : 2944; }

// ---------------------------------------------------------------------------
// Kernel 1: build J_l = expm(pi*(X0+X1)/sqrt(2)) in fp64 (order 24, 10 sq).
// One block per l (l = blockIdx.x+1). Verified round 1.
// ---------------------------------------------------------------------------
__global__ __launch_bounds__(128) void build_J(float* __restrict__ Jout)
{
    const int l = blockIdx.x + 1;
    const int d = 2*l + 1;
    const int dd = d*d;
    const int tid = threadIdx.x;
    __shared__ double Qr[81], Qi[81], Xr[81], Xi[81];
    __shared__ double M1r[81], M1i[81];
    __shared__ double Am[81], Em[81], Tm[81], Tn[81];

    if (tid == 0) {
        for (int e = 0; e < dd; ++e) { Qr[e]=0; Qi[e]=0; Xr[e]=0; Xi[e]=0; }
        const double jj = (double)l;
        for (int i = 0; i < d-1; ++i) {
            double mm = -jj + (double)i;
            Xr[(i+1)*d + i] += 0.5 * (-sqrt(jj*(jj+1.0) - mm*(mm+1.0)));
            double m2 = -jj + 1.0 + (double)i;
            Xr[i*d + (i+1)] += 0.5 * ( sqrt(jj*(jj+1.0) - m2*(m2-1.0)));
        }
        for (int i = 0; i < d; ++i) Xi[i*d + i] = -jj + (double)i;
        const double is2 = 1.0 / sqrt(2.0);
        for (int mm = -l; mm < 0; ++mm) {
            int r = l + mm;
            Qr[r*d + (l - mm)] = is2;
            Qi[r*d + (l + mm)] = -is2;
        }
        Qr[l*d + l] = 1.0;
        for (int mm = 1; mm <= l; ++mm) {
            int r = l + mm;
            double sgn = (mm & 1) ? -1.0 : 1.0;
            Qr[r*d + (l + mm)] = sgn * is2;
            Qi[r*d + (l - mm)] = sgn * is2;
        }
        double fr, fi;                       // (-i)^l
        switch (l & 3) {
            case 0: fr = 1;  fi = 0;  break;
            case 1: fr = 0;  fi = -1; break;
            case 2: fr = -1; fi = 0;  break;
            default: fr = 0; fi = 1;  break;
        }
        for (int e = 0; e < dd; ++e) {
            double qr = Qr[e], qi = Qi[e];
            Qr[e] = qr*fr - qi*fi;
            Qi[e] = qr*fi + qi*fr;
        }
    }
    __syncthreads();
    const int i = tid / d;
    const int j = tid % d;
    if (tid < dd) {                          // M1 = X @ Q (complex)
        double ar = 0, ai = 0;
        for (int k = 0; k < d; ++k) {
            double xr = Xr[i*d+k], xi = Xi[i*d+k];
            double qr = Qr[k*d+j], qi = Qi[k*d+j];
            ar += xr*qr - xi*qi;
            ai += xr*qi + xi*qr;
        }
        M1r[tid] = ar; M1i[tid] = ai;
    }
    __syncthreads();
    if (tid < dd) {                          // A = Re(Q^H M1) * pi/sqrt2 / 2^10
        double ar = 0;
        for (int k = 0; k < d; ++k)
            ar += Qr[k*d+i]*M1r[k*d+j] + Qi[k*d+i]*M1i[k*d+j];
        const double scale = 3.14159265358979323846 / sqrt(2.0) / 1024.0;
        Am[tid] = ar * scale;
        Em[tid] = (i == j) ? 1.0 : 0.0;
        Tm[tid] = (i == j) ? 1.0 : 0.0;
    }
    __syncthreads();
    for (int k = 1; k < 24; ++k) {
        if (tid < dd) {
            double s = 0;
            for (int b = 0; b < d; ++b) s += Tm[i*d+b] * Am[b*d+j];
            Tn[tid] = s / (double)k;
        }
        __syncthreads();
        if (tid < dd) { Tm[tid] = Tn[tid]; Em[tid] += Tn[tid]; }
        __syncthreads();
    }
    for (int s = 0; s < 10; ++s) {
        if (tid < dd) {
            double v = 0;
            for (int b = 0; b < d; ++b) v += Em[i*d+b] * Em[b*d+j];
            Tn[tid] = v;
        }
        __syncthreads();
        if (tid < dd) Em[tid] = Tn[tid];
        __syncthreads();
    }
    if (tid < dd) Jout[joff_of(l) + tid] = (float)Em[tid];
}

// ---------------------------------------------------------------------------
// Kernel 2: bf16 effective weights (verified round 1).
// ---------------------------------------------------------------------------
__global__ __launch_bounds__(256) void prep_w(
    const float* __restrict__ fc0_w,
    const float* __restrict__ w1, const float* __restrict__ w2,
    const float* __restrict__ w3, const float* __restrict__ w4,
    __hip_bfloat16* __restrict__ Wall)
{
    const int m = blockIdx.y;
    const int idx = blockIdx.x * 256 + threadIdx.x;
    if (m == 0) {
        if (idx < 640*640) Wall[idx] = __float2bfloat16(fc0_w[idx]);
        return;
    }
    const int co = 128 * (5 - m);
    const int C  = 2 * co;
    if (idx >= C*C) return;
    const float* wm = (m==1) ? w1 : (m==2) ? w2 : (m==3) ? w3 : w4;
    const int jj = idx / C;
    const int tt = idx - jj * C;
    float v;
    if (jj < co) {
        v = (tt < co) ? wm[jj*co + tt] : -wm[(co + jj)*co + (tt - co)];
    } else {
        v = (tt < co) ? wm[jj*co + tt] :  wm[(jj - co)*co + (tt - co)];
    }
    Wall[c_WO[m] + idx] = __float2bfloat16(v);
}

// ---------------------------------------------------------------------------
// Kernel 3a: per-row trig table. trig[row*20 + {0..4:cA, 5..9:sA, 10..14:cB, 15..19:sB}]
// ---------------------------------------------------------------------------
__global__ __launch_bounds__(256) void build_trig(
    const float* __restrict__ R, float* __restrict__ trig)
{
    const int row = blockIdx.x * 256 + threadIdx.x;
    if (row >= N_ROWS) return;
    float r0 = R[row*3+0], r1 = R[row*3+1], r2 = R[row*3+2];
    float nrm = sqrtf(r0*r0 + r1*r1 + r2*r2);
    nrm = fmaxf(nrm, 1e-12f);
    float vx = r1/nrm, vy = r2/nrm, vz = r0/nrm;
    vx = fminf(1.f, fmaxf(-1.f, vx));
    vy = fminf(1.f, fmaxf(-1.f, vy));
    vz = fminf(1.f, fmaxf(-1.f, vz));
    float beta  = acosf(vy);
    float alpha = atan2f(vx, vz);
    float* t = trig + row*20;
#pragma unroll
    for (int m = 0; m < 5; ++m) {
        float s, c;
        sincosf(alpha * (float)m, &s, &c);
        t[m] = c; t[5+m] = s;
        sincosf(beta * (float)m, &s, &c);
        t[10+m] = c; t[15+m] = s;
    }
}

// ---------------------------------------------------------------------------
// Kernel 3b: D matrices, thread per (row, entry). D = Za @ ((J Zb) J).
// Formulas identical to verified round-1 in-block build.
// ---------------------------------------------------------------------------
__global__ __launch_bounds__(256) void build_D(
    const float* __restrict__ Jws, const float* __restrict__ trig,
    float* __restrict__ Dws)
{
    const int gid = blockIdx.x * 256 + threadIdx.x;
    if (gid >= N_ROWS * 164) return;
    const int row = gid / 164;
    const int e   = gid - row * 164;
    int l, base;
    if (e < 9)       { l = 1; base = 0;  }
    else if (e < 34) { l = 2; base = 9;  }
    else if (e < 83) { l = 3; base = 34; }
    else             { l = 4; base = 83; }
    const int d = 2*l + 1;
    const int loc = e - base;
    const int i = loc / d, j = loc - i*d;
    const float* Jp = Jws + base;
    const float* t  = trig + row*20;
    float pij = 0.f, pdj = 0.f;
    for (int b = 0; b < d; ++b) {
        int f = l - b; int af = f < 0 ? -f : f;
        float cb = t[10 + af];
        float sb = (b >= l) ? t[15 + b - l] : -t[15 + l - b];
        float zr  = Jp[i*d + b]*cb + Jp[i*d + (d-1-b)]*sb;
        float zr2 = Jp[(d-1-i)*d + b]*cb + Jp[(d-1-i)*d + (d-1-b)]*sb;
        float jb  = Jp[b*d + j];
        pij += zr  * jb;
        pdj += zr2 * jb;
    }
    int f = l - i; int af = f < 0 ? -f : f;
    float ca = t[af];
    float sa = (f > 0) ? t[5 + f] : ((f < 0) ? -t[5 + af] : 0.f);
    Dws[gid] = ca * pij + sa * pdj;
}

// ---------------------------------------------------------------------------
// Rotation channel helpers (no LDS; packed 4B writes/reads for the +/-m pairs)
// ---------------------------------------------------------------------------
template<int L>
__device__ __forceinline__ void rot_one(const float* __restrict__ xr,
                                        const float* __restrict__ Dl,
                                        __hip_bfloat16* __restrict__ Urow, int k)
{
    constexpr int d = 2*L + 1;
    float xv[d], y[d];
    const float* xp = xr + 128*L*L + k*d;
#pragma unroll
    for (int j = 0; j < d; ++j) xv[j] = xp[j];
#pragma unroll
    for (int q = 0; q < d; ++q) {
        float acc = 0.f;
#pragma unroll
        for (int j = 0; j < d; ++j) acc += Dl[j*d + q] * xv[j];
        y[q] = acc;
    }
    Urow[L*128 + k] = __float2bfloat16(y[L]);            // m=0
#pragma unroll
    for (int m = 1; m <= L; ++m) {                        // (-m,+m) pair -> one 4B store
        unsigned short lo = __builtin_bit_cast(unsigned short, __float2bfloat16(y[L-m]));
        unsigned short hi = __builtin_bit_cast(unsigned short, __float2bfloat16(y[L+m]));
        unsigned int pack = ((unsigned int)hi << 16) | lo;
        *(unsigned int*)(Urow + gO(m) + 2*((L-m)*128 + k)) = pack;
    }
}

template<int L>
__device__ __forceinline__ void unrot_one(const __hip_bfloat16* __restrict__ Yrow,
                                          const float* __restrict__ Dl,
                                          float* __restrict__ orow, int k)
{
    constexpr int d = 2*L + 1;
    float yv[d];
    yv[L] = __bfloat162float(Yrow[L*128 + k]);
#pragma unroll
    for (int m = 1; m <= L; ++m) {
        unsigned int pack = *(const unsigned int*)(Yrow + gO(m) + 2*((L-m)*128 + k));
        unsigned short lo = (unsigned short)(pack & 0xffffu);
        unsigned short hi = (unsigned short)(pack >> 16);
        yv[L-m] = __bfloat162float(__builtin_bit_cast(__hip_bfloat16, lo));
        yv[L+m] = __bfloat162float(__builtin_bit_cast(__hip_bfloat16, hi));
    }
    float* op = orow + 128*L*L + k*d;
#pragma unroll
    for (int i = 0; i < d; ++i) {
        float acc = 0.f;
#pragma unroll
        for (int j = 0; j < d; ++j) acc += Dl[j*d + i] * yv[j];
        op[i] = acc;
    }
}

// ---------------------------------------------------------------------------
// Kernel 4: rotate+gather, thread per (row, channel). 640 = 5*128 channels/row
// so waves never straddle rows and l is wave-uniform. No LDS, no barriers.
// ---------------------------------------------------------------------------
__global__ __launch_bounds__(256) void rot_gather(
    const float* __restrict__ x, const float* __restrict__ Dws,
    __hip_bfloat16* __restrict__ U)
{
    const int gid = blockIdx.x * 256 + threadIdx.x;
    const int row = gid / 640;
    const int c   = gid - row * 640;
    const int l = c >> 7, k = c & 127;
    const float* xr = x + (size_t)row * DIM;
    __hip_bfloat16* Urow = U + (size_t)row * DIM;
    const float* Dm = Dws + (size_t)row * 164;
    switch (l) {
        case 0: Urow[k] = __float2bfloat16(0.f); break;   // l=0 inputs dropped
        case 1: rot_one<1>(xr, Dm + 0,  Urow, k); break;
        case 2: rot_one<2>(xr, Dm + 9,  Urow, k); break;
        case 3: rot_one<3>(xr, Dm + 34, Urow, k); break;
        case 4: rot_one<4>(xr, Dm + 83, Urow, k); break;
    }
}

// ---------------------------------------------------------------------------
// Kernel 5: BT GEMM, 256x256 tile, 4-deep LDS ring pipeline (BK=32 per phase),
// counted vmcnt (never 0 in loop), XOR-swizzled LDS (<=2-way bank aliasing),
// setprio around MFMA cluster, bijective XCD swizzle over 832 blocks.
//   Y[r,O+j] = sum_t U[r,O+t]*W[j,t]  (+bias for m=0)
// Correctness ledger:
//  - 4 stage loads/thread/tile; 3 tiles (12 loads) always in flight.
//  - phase kt: reads buf[kt&3]; stages tile kt+3 into buf[(kt+3)&3]
//    (holds tile kt-1, whose ds_reads completed before the phase-(kt-1)
//    barrier every thread has passed).
//  - vmcnt(8) at phase end retires the 4 oldest loads = tile kt+1; barrier
//    then makes buf[(kt+1)&3] globally valid for the next phase's ds_reads.
//  - tail phases re-stage tile NT-1 into dead buffers to keep the vmcnt
//    ledger uniform.
// ---------------------------------------------------------------------------
__device__ __forceinline__ void g2lds16(const void* g, void* l) {
    __builtin_amdgcn_global_load_lds(
        (const __attribute__((address_space(1))) void*)g,
        (__attribute__((address_space(3))) void*)l, 16, 0, 0);
}

__device__ __forceinline__ int swz(int x) { return x ^ (((x >> 7) & 7) << 4); }

__global__ __launch_bounds__(512, 2) void gemm_bt(
    const __hip_bfloat16* __restrict__ U, const __hip_bfloat16* __restrict__ W,
    const float* __restrict__ bias, __hip_bfloat16* __restrict__ Y)
{
    // bijective XCD swizzle (832 % 8 == 0): each XCD gets 104 consecutive wg,
    // row-panel-major so co-resident blocks share the same 256-row A panel.
    const int bid = blockIdx.x;
    const int wg  = (bid & 7) * 104 + (bid >> 3);
    const int rt  = wg / 13;
    const int ct  = wg - rt * 13;
    const int m   = c_m13[ct];
    const int nt2 = c_nt13[ct];
    const int K   = c_K[m];
    const int NT  = K >> 5;                  // K-tiles of 32; NT in {20,32,24,16,8}
    const int row0 = rt * 256;

    const __hip_bfloat16* Ablk = U + (size_t)row0 * DIM + c_UO[m];
    const __hip_bfloat16* Bblk = W + c_WO[m] + (size_t)nt2 * 256 * K;

    // ring: A bufs at [cb*16384, +16K), B bufs at [65536 + cb*16384, +16K)
    // each buffer: logical (idx256, k32) stored as [row=idx&127][128B], with
    // the idx>=128 half in the upper 64B of the row; bytes XOR-swizzled.
    __shared__ __align__(16) char lds[131072];

    const int tid  = threadIdx.x;
    const int lane = tid & 63, w = tid >> 6;
    const int frow = lane & 15, quad = lane >> 4;
    const int wmi  = w >> 2, wni = w & 3;    // 2 M-waves x 4 N-waves

    // ---- per-thread stage sources (pre-swizzled: linear LDS dest o gets the
    // logical chunk swz(o); swz is an involution) ----
    const __hip_bfloat16* srcA[2];
    const __hip_bfloat16* srcB[2];
#pragma unroll
    for (int t = 0; t < 2; ++t) {
        const int o   = tid * 16 + t * 8192;      // phys byte offset in buffer
        const int lam = swz(o);                   // logical byte offset
        const int row = lam >> 7, colb = lam & 127;
        const int idx = row + ((colb >> 6) & 1) * 128;   // 0..255 (m or n)
        const int ke  = (colb & 63) >> 1;                // k element 0..31 (x8 aligned)
        srcA[t] = Ablk + (size_t)(idx) * DIM + ke;
        srcB[t] = Bblk + (size_t)(idx) * K   + ke;
    }

    // ---- fragment read offsets (constant across phases) ----
    int aoff[8], boff[4];
#pragma unroll
    for (int i = 0; i < 8; ++i)
        aoff[i] = swz((i*16 + frow) * 128 + wmi * 64 + quad * 16);
#pragma unroll
    for (int j = 0; j < 4; ++j)
        boff[j] = swz(((wni & 1) * 64 + j*16 + frow) * 128 + (wni >> 1) * 64 + quad * 16);

    floatx4 acc[8][4];
#pragma unroll
    for (int i = 0; i < 8; ++i)
#pragma unroll
        for (int j = 0; j < 4; ++j) acc[i][j] = (floatx4){0.f, 0.f, 0.f, 0.f};

    // ---- prologue: stage tiles 0,1,2 ----
#pragma unroll
    for (int p = 0; p < 3; ++p) {
        char* Ad = lds + p * 16384;
        char* Bd = lds + 65536 + p * 16384;
        g2lds16(srcA[0] + p*32, Ad + w*1024);
        g2lds16(srcA[1] + p*32, Ad + 8192 + w*1024);
        g2lds16(srcB[0] + p*32, Bd + w*1024);
        g2lds16(srcB[1] + p*32, Bd + 8192 + w*1024);
    }
    __builtin_amdgcn_sched_barrier(0);
    asm volatile("s_waitcnt vmcnt(8)" ::: "memory");   // tile 0 landed
    __builtin_amdgcn_s_barrier();
    __builtin_amdgcn_sched_barrier(0);

    for (int kt = 0; kt < NT; ++kt) {
        const char* Ab = lds + (kt & 3) * 16384;
        const char* Bb = lds + 65536 + (kt & 3) * 16384;
        short8 a[8], b[4];
#pragma unroll
        for (int i = 0; i < 8; ++i) a[i] = *(const short8*)(Ab + aoff[i]);
#pragma unroll
        for (int j = 0; j < 4; ++j) b[j] = *(const short8*)(Bb + boff[j]);

        {   // stage tile kt+3 (clamped source keeps the vmcnt ledger uniform)
            int ks = kt + 3; if (ks > NT - 1) ks = NT - 1;
            char* Ad = lds + ((kt + 3) & 3) * 16384;
            char* Bd = lds + 65536 + ((kt + 3) & 3) * 16384;
            g2lds16(srcA[0] + ks*32, Ad + w*1024);
            g2lds16(srcA[1] + ks*32, Ad + 8192 + w*1024);
            g2lds16(srcB[0] + ks*32, Bd + w*1024);
            g2lds16(srcB[1] + ks*32, Bd + 8192 + w*1024);
        }
        __builtin_amdgcn_sched_barrier(0);

        __builtin_amdgcn_s_setprio(1);
#pragma unroll
        for (int i = 0; i < 8; ++i)
#pragma unroll
            for (int j = 0; j < 4; ++j)
                acc[i][j] = __builtin_amdgcn_mfma_f32_16x16x32_bf16(a[i], b[j], acc[i][j], 0, 0, 0);
        __builtin_amdgcn_s_setprio(0);

        __builtin_amdgcn_sched_barrier(0);
        asm volatile("s_waitcnt vmcnt(8)" ::: "memory"); // tile kt+1 landed
        __builtin_amdgcn_s_barrier();
        __builtin_amdgcn_sched_barrier(0);
    }
    asm volatile("s_waitcnt vmcnt(0)" ::: "memory");     // drain dangling stages

    // ---- epilogue: clamped stores (m0 tile 2 covers cols 512..767, K=640) ----
#pragma unroll
    for (int i = 0; i < 8; ++i) {
        const int grow = row0 + wmi*128 + i*16 + quad*4;
#pragma unroll
        for (int j = 0; j < 4; ++j) {
            const int col = nt2*256 + wni*64 + j*16 + frow;   // within m-block
            if (col < K) {
                const float bv = (m == 0) ? bias[col] : 0.f;
                const size_t cg = (size_t)c_UO[m] + col;
#pragma unroll
                for (int r = 0; r < 4; ++r)
                    Y[(size_t)(grow + r)*DIM + cg] = __float2bfloat16(acc[i][j][r] + bv);
            }
        }
    }
}

// ---------------------------------------------------------------------------
// Kernel 6: un-gather + second rotation + fp32 store. Thread per (row,channel).
// ---------------------------------------------------------------------------
__global__ __launch_bounds__(256) void ungather_rot(
    const __hip_bfloat16* __restrict__ Y, const float* __restrict__ Dws,
    float* __restrict__ out)
{
    const int gid = blockIdx.x * 256 + threadIdx.x;
    const int row = gid / 640;
    const int c   = gid - row * 640;
    const int l = c >> 7, k = c & 127;
    const __hip_bfloat16* Yrow = Y + (size_t)row * DIM;
    float* orow = out + (size_t)row * DIM;
    const float* Dm = Dws + (size_t)row * 164;
    switch (l) {
        case 0: orow[k] = __bfloat162float(Yrow[k]); break;   // l=0 passthrough
        case 1: unrot_one<1>(Yrow, Dm + 0,  orow, k); break;
        case 2: unrot_one<2>(Yrow, Dm + 9,  orow, k); break;
        case 3: unrot_one<3>(Yrow, Dm + 34, orow, k); break;
        case 4: unrot_one<4>(Yrow, Dm + 83, orow, k); break;
    }
}

// ---------------------------------------------------------------------------
extern "C" void kernel_launch(void* const* d_in, const int* in_sizes, int n_in,
                              void* d_out, int out_size, void* d_ws, size_t ws_size,
                              hipStream_t stream)
{
    (void)in_sizes; (void)n_in; (void)out_size; (void)ws_size;
    const float* x     = (const float*)d_in[0];
    const float* R     = (const float*)d_in[1];
    const float* fc0_w = (const float*)d_in[2];
    const float* fc0_b = (const float*)d_in[3];
    const float* w1    = (const float*)d_in[4];
    const float* w2    = (const float*)d_in[5];
    const float* w3    = (const float*)d_in[6];
    const float* w4    = (const float*)d_in[7];
    float* out = (float*)d_out;

    // workspace layout (bytes):
    //   J     @ 0           (656, padded to 1024)
    //   Wall  @ 1024        (4,751,360)
    //   Dws   @ 4,752,384   (10,747,904)
    //   U     @ 15,500,288  (104,857,600)
    //   Y     @ 120,357,888 (104,857,600)  -> total 225,215,488
    //   trig aliased onto Y's first 1.31 MB (dead before gemm writes Y)
    char* ws = (char*)d_ws;
    float*          Jws  = (float*)ws;
    __hip_bfloat16* Wall = (__hip_bfloat16*)(ws + 1024);
    float*          Dws  = (float*)(ws + 4752384);
    __hip_bfloat16* U    = (__hip_bfloat16*)(ws + 15500288);
    __hip_bfloat16* Y    = (__hip_bfloat16*)(ws + 120357888);
    float*          trig = (float*)(ws + 120357888);   // alias, see above

    build_J     <<<dim3(4),         dim3(128), 0, stream>>>(Jws);
    prep_w      <<<dim3(4096, 5),   dim3(256), 0, stream>>>(fc0_w, w1, w2, w3, w4, Wall);
    build_trig  <<<dim3(64),        dim3(256), 0, stream>>>(R, trig);
    build_D     <<<dim3(10496),     dim3(256), 0, stream>>>(Jws, trig, Dws);
    rot_gather  <<<dim3(40960),     dim3(256), 0, stream>>>(x, Dws, U);
    gemm_bt     <<<dim3(832),       dim3(512), 0, stream>>>(U, Wall, fc0_b, Y);
    ungather_rot<<<dim3(40960),     dim3(256), 0, stream>>>(Y, Dws, out);
}

// Round 2
// 633.966 us; speedup vs baseline: 1.0733x; 1.0470x over previous
//
#include <hip/hip_runtime.h>
#include <hip/hip_bf16.h>
#include <math.h>

// Problem constants: MUL=128, LS=0..4, DIM=3200, N=16384
// gathered layout: m-blocks width C[m]={640,1024,768,512,256}, offsets {0,640,1664,2432,2944}
#define N_ROWS 16384
#define DIM    3200

using short8  = __attribute__((ext_vector_type(8))) short;
using floatx4 = __attribute__((ext_vector_type(4))) float;

__device__ const int c_K [5] = {640, 1024, 768, 512, 256};
__device__ const int c_UO[5] = {0, 640, 1664, 2432, 2944};
__device__ const int c_WO[5] = {0, 409600, 1458176, 2048000, 2310144};
// 13 column tiles of width 256 across the 5 m-blocks (m0 ragged: 640 = 2.5 tiles, clamped)
__device__ const int c_m13 [13] = {0,0,0, 1,1,1,1, 2,2,2, 3,3, 4};
__device__ const int c_nt13[13] = {0,1,2, 0,1,2,3, 0,1,2, 0,1, 0};

__device__ __forceinline__ constexpr int joff_of(int l) { return l==1 ? 0 : l==2 ? 9 : l==3 ? 34 : 83; }
__device__ __forceinline__ constexpr int gO(int m)      { return m==1 ? 640 : m==2 ? 1664 : m==3 ? 2432 : 2944; }

// ---------------------------------------------------------------------------
// Kernel 1: build J_l = expm(pi*(X0+X1)/sqrt(2)) in fp64 (order 24, 10 sq).
// One block per l (l = blockIdx.x+1). Verified round 1.
// ---------------------------------------------------------------------------
__global__ __launch_bounds__(128) void build_J(float* __restrict__ Jout)
{
    const int l = blockIdx.x + 1;
    const int d = 2*l + 1;
    const int dd = d*d;
    const int tid = threadIdx.x;
    __shared__ double Qr[81], Qi[81], Xr[81], Xi[81];
    __shared__ double M1r[81], M1i[81];
    __shared__ double Am[81], Em[81], Tm[81], Tn[81];

    if (tid == 0) {
        for (int e = 0; e < dd; ++e) { Qr[e]=0; Qi[e]=0; Xr[e]=0; Xi[e]=0; }
        const double jj = (double)l;
        for (int i = 0; i < d-1; ++i) {
            double mm = -jj + (double)i;
            Xr[(i+1)*d + i] += 0.5 * (-sqrt(jj*(jj+1.0) - mm*(mm+1.0)));
            double m2 = -jj + 1.0 + (double)i;
            Xr[i*d + (i+1)] += 0.5 * ( sqrt(jj*(jj+1.0) - m2*(m2-1.0)));
        }
        for (int i = 0; i < d; ++i) Xi[i*d + i] = -jj + (double)i;
        const double is2 = 1.0 / sqrt(2.0);
        for (int mm = -l; mm < 0; ++mm) {
            int r = l + mm;
            Qr[r*d + (l - mm)] = is2;
            Qi[r*d + (l + mm)] = -is2;
        }
        Qr[l*d + l] = 1.0;
        for (int mm = 1; mm <= l; ++mm) {
            int r = l + mm;
            double sgn = (mm & 1) ? -1.0 : 1.0;
            Qr[r*d + (l + mm)] = sgn * is2;
            Qi[r*d + (l - mm)] = sgn * is2;
        }
        double fr, fi;                       // (-i)^l
        switch (l & 3) {
            case 0: fr = 1;  fi = 0;  break;
            case 1: fr = 0;  fi = -1; break;
            case 2: fr = -1; fi = 0;  break;
            default: fr = 0; fi = 1;  break;
        }
        for (int e = 0; e < dd; ++e) {
            double qr = Qr[e], qi = Qi[e];
            Qr[e] = qr*fr - qi*fi;
            Qi[e] = qr*fi + qi*fr;
        }
    }
    __syncthreads();
    const int i = tid / d;
    const int j = tid % d;
    if (tid < dd) {                          // M1 = X @ Q (complex)
        double ar = 0, ai = 0;
        for (int k = 0; k < d; ++k) {
            double xr = Xr[i*d+k], xi = Xi[i*d+k];
            double qr = Qr[k*d+j], qi = Qi[k*d+j];
            ar += xr*qr - xi*qi;
            ai += xr*qi + xi*qr;
        }
        M1r[tid] = ar; M1i[tid] = ai;
    }
    __syncthreads();
    if (tid < dd) {                          // A = Re(Q^H M1) * pi/sqrt2 / 2^10
        double ar = 0;
        for (int k = 0; k < d; ++k)
            ar += Qr[k*d+i]*M1r[k*d+j] + Qi[k*d+i]*M1i[k*d+j];
        const double scale = 3.14159265358979323846 / sqrt(2.0) / 1024.0;
        Am[tid] = ar * scale;
        Em[tid] = (i == j) ? 1.0 : 0.0;
        Tm[tid] = (i == j) ? 1.0 : 0.0;
    }
    __syncthreads();
    for (int k = 1; k < 24; ++k) {
        if (tid < dd) {
            double s = 0;
            for (int b = 0; b < d; ++b) s += Tm[i*d+b] * Am[b*d+j];
            Tn[tid] = s / (double)k;
        }
        __syncthreads();
        if (tid < dd) { Tm[tid] = Tn[tid]; Em[tid] += Tn[tid]; }
        __syncthreads();
    }
    for (int s = 0; s < 10; ++s) {
        if (tid < dd) {
            double v = 0;
            for (int b = 0; b < d; ++b) v += Em[i*d+b] * Em[b*d+j];
            Tn[tid] = v;
        }
        __syncthreads();
        if (tid < dd) Em[tid] = Tn[tid];
        __syncthreads();
    }
    if (tid < dd) Jout[joff_of(l) + tid] = (float)Em[tid];
}

// ---------------------------------------------------------------------------
// Kernel 2: bf16 effective weights (verified round 1).
// ---------------------------------------------------------------------------
__global__ __launch_bounds__(256) void prep_w(
    const float* __restrict__ fc0_w,
    const float* __restrict__ w1, const float* __restrict__ w2,
    const float* __restrict__ w3, const float* __restrict__ w4,
    __hip_bfloat16* __restrict__ Wall)
{
    const int m = blockIdx.y;
    const int idx = blockIdx.x * 256 + threadIdx.x;
    if (m == 0) {
        if (idx < 640*640) Wall[idx] = __float2bfloat16(fc0_w[idx]);
        return;
    }
    const int co = 128 * (5 - m);
    const int C  = 2 * co;
    if (idx >= C*C) return;
    const float* wm = (m==1) ? w1 : (m==2) ? w2 : (m==3) ? w3 : w4;
    const int jj = idx / C;
    const int tt = idx - jj * C;
    float v;
    if (jj < co) {
        v = (tt < co) ? wm[jj*co + tt] : -wm[(co + jj)*co + (tt - co)];
    } else {
        v = (tt < co) ? wm[jj*co + tt] :  wm[(jj - co)*co + (tt - co)];
    }
    Wall[c_WO[m] + idx] = __float2bfloat16(v);
}

// ---------------------------------------------------------------------------
// Kernel 3a: per-row trig table. trig[row*20 + {0..4:cA, 5..9:sA, 10..14:cB, 15..19:sB}]
// ---------------------------------------------------------------------------
__global__ __launch_bounds__(256) void build_trig(
    const float* __restrict__ R, float* __restrict__ trig)
{
    const int row = blockIdx.x * 256 + threadIdx.x;
    if (row >= N_ROWS) return;
    float r0 = R[row*3+0], r1 = R[row*3+1], r2 = R[row*3+2];
    float nrm = sqrtf(r0*r0 + r1*r1 + r2*r2);
    nrm = fmaxf(nrm, 1e-12f);
    float vx = r1/nrm, vy = r2/nrm, vz = r0/nrm;
    vx = fminf(1.f, fmaxf(-1.f, vx));
    vy = fminf(1.f, fmaxf(-1.f, vy));
    vz = fminf(1.f, fmaxf(-1.f, vz));
    float beta  = acosf(vy);
    float alpha = atan2f(vx, vz);
    float* t = trig + row*20;
#pragma unroll
    for (int m = 0; m < 5; ++m) {
        float s, c;
        sincosf(alpha * (float)m, &s, &c);
        t[m] = c; t[5+m] = s;
        sincosf(beta * (float)m, &s, &c);
        t[10+m] = c; t[15+m] = s;
    }
}

// ---------------------------------------------------------------------------
// Kernel 3b: D matrices, thread per (row, entry). D = Za @ ((J Zb) J).
// Formulas identical to verified round-1 in-block build.
// ---------------------------------------------------------------------------
__global__ __launch_bounds__(256) void build_D(
    const float* __restrict__ Jws, const float* __restrict__ trig,
    float* __restrict__ Dws)
{
    const int gid = blockIdx.x * 256 + threadIdx.x;
    if (gid >= N_ROWS * 164) return;
    const int row = gid / 164;
    const int e   = gid - row * 164;
    int l, base;
    if (e < 9)       { l = 1; base = 0;  }
    else if (e < 34) { l = 2; base = 9;  }
    else if (e < 83) { l = 3; base = 34; }
    else             { l = 4; base = 83; }
    const int d = 2*l + 1;
    const int loc = e - base;
    const int i = loc / d, j = loc - i*d;
    const float* Jp = Jws + base;
    const float* t  = trig + row*20;
    float pij = 0.f, pdj = 0.f;
    for (int b = 0; b < d; ++b) {
        int f = l - b; int af = f < 0 ? -f : f;
        float cb = t[10 + af];
        float sb = (b >= l) ? t[15 + b - l] : -t[15 + l - b];
        float zr  = Jp[i*d + b]*cb + Jp[i*d + (d-1-b)]*sb;
        float zr2 = Jp[(d-1-i)*d + b]*cb + Jp[(d-1-i)*d + (d-1-b)]*sb;
        float jb  = Jp[b*d + j];
        pij += zr  * jb;
        pdj += zr2 * jb;
    }
    int f = l - i; int af = f < 0 ? -f : f;
    float ca = t[af];
    float sa = (f > 0) ? t[5 + f] : ((f < 0) ? -t[5 + af] : 0.f);
    Dws[gid] = ca * pij + sa * pdj;
}

// ---------------------------------------------------------------------------
// Rotation channel helpers (operate on LDS-staged rows; packed 4B accesses for
// the +/-m pairs). Arithmetic identical to the verified round-1 versions.
// ---------------------------------------------------------------------------
template<int L>
__device__ __forceinline__ void rot_one(const float* __restrict__ xr,
                                        const float* __restrict__ Dl,
                                        __hip_bfloat16* __restrict__ Urow, int k)
{
    constexpr int d = 2*L + 1;
    float xv[d], y[d];
    const float* xp = xr + 128*L*L + k*d;
#pragma unroll
    for (int j = 0; j < d; ++j) xv[j] = xp[j];
#pragma unroll
    for (int q = 0; q < d; ++q) {
        float acc = 0.f;
#pragma unroll
        for (int j = 0; j < d; ++j) acc += Dl[j*d + q] * xv[j];
        y[q] = acc;
    }
    Urow[L*128 + k] = __float2bfloat16(y[L]);            // m=0
#pragma unroll
    for (int m = 1; m <= L; ++m) {                        // (-m,+m) pair -> one 4B store
        unsigned short lo = __builtin_bit_cast(unsigned short, __float2bfloat16(y[L-m]));
        unsigned short hi = __builtin_bit_cast(unsigned short, __float2bfloat16(y[L+m]));
        unsigned int pack = ((unsigned int)hi << 16) | lo;
        *(unsigned int*)(Urow + gO(m) + 2*((L-m)*128 + k)) = pack;
    }
}

template<int L>
__device__ __forceinline__ void unrot_one(const __hip_bfloat16* __restrict__ Yrow,
                                          const float* __restrict__ Dl,
                                          float* __restrict__ orow, int k)
{
    constexpr int d = 2*L + 1;
    float yv[d];
    yv[L] = __bfloat162float(Yrow[L*128 + k]);
#pragma unroll
    for (int m = 1; m <= L; ++m) {
        unsigned int pack = *(const unsigned int*)(Yrow + gO(m) + 2*((L-m)*128 + k));
        unsigned short lo = (unsigned short)(pack & 0xffffu);
        unsigned short hi = (unsigned short)(pack >> 16);
        yv[L-m] = __bfloat162float(__builtin_bit_cast(__hip_bfloat16, lo));
        yv[L+m] = __bfloat162float(__builtin_bit_cast(__hip_bfloat16, hi));
    }
    float* op = orow + 128*L*L + k*d;
#pragma unroll
    for (int i = 0; i < d; ++i) {
        float acc = 0.f;
#pragma unroll
        for (int j = 0; j < d; ++j) acc += Dl[j*d + i] * yv[j];
        op[i] = acc;
    }
}

// ---------------------------------------------------------------------------
// Kernel 4: rotate+gather, LDS-staged. Block = 256 threads handles 2 rows:
// coop float4 load of x rows + D rows into LDS, then 5 channels/thread with
// x/D read from LDS (D is wave-uniform -> broadcast; x strides d odd ->
// conflict-free). U stores unchanged (coalesced 4B pair stores).
// ---------------------------------------------------------------------------
#define RG_ROWS 2
__global__ __launch_bounds__(256) void rot_gather(
    const float* __restrict__ x, const float* __restrict__ Dws,
    __hip_bfloat16* __restrict__ U)
{
    __shared__ __align__(16) float xs[RG_ROWS][DIM];
    __shared__ float ds[RG_ROWS][164];
    const int tid  = threadIdx.x;
    const int row0 = blockIdx.x * RG_ROWS;

    const float4* xg = (const float4*)(x + (size_t)row0 * DIM);
    float4* xls = (float4*)&xs[0][0];
#pragma unroll
    for (int i = 0; i < (RG_ROWS*DIM/4 + 255)/256; ++i) {
        int p = i*256 + tid;
        if (p < RG_ROWS*DIM/4) xls[p] = xg[p];
    }
    const float* dg = Dws + (size_t)row0 * 164;
    for (int p = tid; p < RG_ROWS*164; p += 256) ((float*)ds)[p] = dg[p];
    __syncthreads();

#pragma unroll
    for (int q = 0; q < RG_ROWS*640/256; ++q) {
        const int idx = q*256 + tid;
        const int r = idx / 640;
        const int c = idx - r*640;
        const int l = c >> 7, k = c & 127;
        const float* xr = xs[r];
        const float* Dm = ds[r];
        __hip_bfloat16* Urow = U + (size_t)(row0 + r) * DIM;
        switch (l) {
            case 0: Urow[k] = __float2bfloat16(0.f); break;   // l=0 inputs dropped
            case 1: rot_one<1>(xr, Dm + 0,  Urow, k); break;
            case 2: rot_one<2>(xr, Dm + 9,  Urow, k); break;
            case 3: rot_one<3>(xr, Dm + 34, Urow, k); break;
            case 4: rot_one<4>(xr, Dm + 83, Urow, k); break;
        }
    }
}

// ---------------------------------------------------------------------------
// Kernel 5: BT GEMM, 256x256 tile, 4-deep LDS ring pipeline (BK=32 per phase),
// counted vmcnt (never 0 in loop), XOR-swizzled LDS, setprio around MFMA
// cluster, bijective XCD swizzle. Verified round 1 (conflicts = 0). Unchanged.
// ---------------------------------------------------------------------------
__device__ __forceinline__ void g2lds16(const void* g, void* l) {
    __builtin_amdgcn_global_load_lds(
        (const __attribute__((address_space(1))) void*)g,
        (__attribute__((address_space(3))) void*)l, 16, 0, 0);
}

__device__ __forceinline__ int swz(int x) { return x ^ (((x >> 7) & 7) << 4); }

__global__ __launch_bounds__(512, 2) void gemm_bt(
    const __hip_bfloat16* __restrict__ U, const __hip_bfloat16* __restrict__ W,
    const float* __restrict__ bias, __hip_bfloat16* __restrict__ Y)
{
    const int bid = blockIdx.x;
    const int wg  = (bid & 7) * 104 + (bid >> 3);
    const int rt  = wg / 13;
    const int ct  = wg - rt * 13;
    const int m   = c_m13[ct];
    const int nt2 = c_nt13[ct];
    const int K   = c_K[m];
    const int NT  = K >> 5;
    const int row0 = rt * 256;

    const __hip_bfloat16* Ablk = U + (size_t)row0 * DIM + c_UO[m];
    const __hip_bfloat16* Bblk = W + c_WO[m] + (size_t)nt2 * 256 * K;

    __shared__ __align__(16) char lds[131072];

    const int tid  = threadIdx.x;
    const int lane = tid & 63, w = tid >> 6;
    const int frow = lane & 15, quad = lane >> 4;
    const int wmi  = w >> 2, wni = w & 3;

    const __hip_bfloat16* srcA[2];
    const __hip_bfloat16* srcB[2];
#pragma unroll
    for (int t = 0; t < 2; ++t) {
        const int o   = tid * 16 + t * 8192;
        const int lam = swz(o);
        const int row = lam >> 7, colb = lam & 127;
        const int idx = row + ((colb >> 6) & 1) * 128;
        const int ke  = (colb & 63) >> 1;
        srcA[t] = Ablk + (size_t)(idx) * DIM + ke;
        srcB[t] = Bblk + (size_t)(idx) * K   + ke;
    }

    int aoff[8], boff[4];
#pragma unroll
    for (int i = 0; i < 8; ++i)
        aoff[i] = swz((i*16 + frow) * 128 + wmi * 64 + quad * 16);
#pragma unroll
    for (int j = 0; j < 4; ++j)
        boff[j] = swz(((wni & 1) * 64 + j*16 + frow) * 128 + (wni >> 1) * 64 + quad * 16);

    floatx4 acc[8][4];
#pragma unroll
    for (int i = 0; i < 8; ++i)
#pragma unroll
        for (int j = 0; j < 4; ++j) acc[i][j] = (floatx4){0.f, 0.f, 0.f, 0.f};

#pragma unroll
    for (int p = 0; p < 3; ++p) {
        char* Ad = lds + p * 16384;
        char* Bd = lds + 65536 + p * 16384;
        g2lds16(srcA[0] + p*32, Ad + w*1024);
        g2lds16(srcA[1] + p*32, Ad + 8192 + w*1024);
        g2lds16(srcB[0] + p*32, Bd + w*1024);
        g2lds16(srcB[1] + p*32, Bd + 8192 + w*1024);
    }
    __builtin_amdgcn_sched_barrier(0);
    asm volatile("s_waitcnt vmcnt(8)" ::: "memory");
    __builtin_amdgcn_s_barrier();
    __builtin_amdgcn_sched_barrier(0);

    for (int kt = 0; kt < NT; ++kt) {
        const char* Ab = lds + (kt & 3) * 16384;
        const char* Bb = lds + 65536 + (kt & 3) * 16384;
        short8 a[8], b[4];
#pragma unroll
        for (int i = 0; i < 8; ++i) a[i] = *(const short8*)(Ab + aoff[i]);
#pragma unroll
        for (int j = 0; j < 4; ++j) b[j] = *(const short8*)(Bb + boff[j]);

        {
            int ks = kt + 3; if (ks > NT - 1) ks = NT - 1;
            char* Ad = lds + ((kt + 3) & 3) * 16384;
            char* Bd = lds + 65536 + ((kt + 3) & 3) * 16384;
            g2lds16(srcA[0] + ks*32, Ad + w*1024);
            g2lds16(srcA[1] + ks*32, Ad + 8192 + w*1024);
            g2lds16(srcB[0] + ks*32, Bd + w*1024);
            g2lds16(srcB[1] + ks*32, Bd + 8192 + w*1024);
        }
        __builtin_amdgcn_sched_barrier(0);

        __builtin_amdgcn_s_setprio(1);
#pragma unroll
        for (int i = 0; i < 8; ++i)
#pragma unroll
            for (int j = 0; j < 4; ++j)
                acc[i][j] = __builtin_amdgcn_mfma_f32_16x16x32_bf16(a[i], b[j], acc[i][j], 0, 0, 0);
        __builtin_amdgcn_s_setprio(0);

        __builtin_amdgcn_sched_barrier(0);
        asm volatile("s_waitcnt vmcnt(8)" ::: "memory");
        __builtin_amdgcn_s_barrier();
        __builtin_amdgcn_sched_barrier(0);
    }
    asm volatile("s_waitcnt vmcnt(0)" ::: "memory");

#pragma unroll
    for (int i = 0; i < 8; ++i) {
        const int grow = row0 + wmi*128 + i*16 + quad*4;
#pragma unroll
        for (int j = 0; j < 4; ++j) {
            const int col = nt2*256 + wni*64 + j*16 + frow;
            if (col < K) {
                const float bv = (m == 0) ? bias[col] : 0.f;
                const size_t cg = (size_t)c_UO[m] + col;
#pragma unroll
                for (int r = 0; r < 4; ++r)
                    Y[(size_t)(grow + r)*DIM + cg] = __float2bfloat16(acc[i][j][r] + bv);
            }
        }
    }
}

// ---------------------------------------------------------------------------
// Kernel 6: un-gather + second rotation, LDS-staged. Block = 256 threads
// handles 2 rows: coop uint4 load of Y rows + D into LDS, compute channels
// into an LDS fp32 out-row, then coop float4 store (coalesced, replaces the
// stride-d fp32 scatter).
// ---------------------------------------------------------------------------
__global__ __launch_bounds__(256) void ungather_rot(
    const __hip_bfloat16* __restrict__ Y, const float* __restrict__ Dws,
    float* __restrict__ out)
{
    __shared__ __align__(16) __hip_bfloat16 ys[RG_ROWS][DIM];
    __shared__ __align__(16) float os[RG_ROWS][DIM];
    __shared__ float ds[RG_ROWS][164];
    const int tid  = threadIdx.x;
    const int row0 = blockIdx.x * RG_ROWS;

    const uint4* yg = (const uint4*)(Y + (size_t)row0 * DIM);
    uint4* yls = (uint4*)&ys[0][0];
#pragma unroll
    for (int i = 0; i < (RG_ROWS*DIM/8 + 255)/256; ++i) {
        int p = i*256 + tid;
        if (p < RG_ROWS*DIM/8) yls[p] = yg[p];
    }
    const float* dg = Dws + (size_t)row0 * 164;
    for (int p = tid; p < RG_ROWS*164; p += 256) ((float*)ds)[p] = dg[p];
    __syncthreads();

#pragma unroll
    for (int q = 0; q < RG_ROWS*640/256; ++q) {
        const int idx = q*256 + tid;
        const int r = idx / 640;
        const int c = idx - r*640;
        const int l = c >> 7, k = c & 127;
        const __hip_bfloat16* Yrow = ys[r];
        const float* Dm = ds[r];
        float* orow = os[r];
        switch (l) {
            case 0: orow[k] = __bfloat162float(Yrow[k]); break;   // l=0 passthrough
            case 1: unrot_one<1>(Yrow, Dm + 0,  orow, k); break;
            case 2: unrot_one<2>(Yrow, Dm + 9,  orow, k); break;
            case 3: unrot_one<3>(Yrow, Dm + 34, orow, k); break;
            case 4: unrot_one<4>(Yrow, Dm + 83, orow, k); break;
        }
    }
    __syncthreads();

    float4* og = (float4*)(out + (size_t)row0 * DIM);
    const float4* ols = (const float4*)&os[0][0];
#pragma unroll
    for (int i = 0; i < (RG_ROWS*DIM/4 + 255)/256; ++i) {
        int p = i*256 + tid;
        if (p < RG_ROWS*DIM/4) og[p] = ols[p];
    }
}

// ---------------------------------------------------------------------------
extern "C" void kernel_launch(void* const* d_in, const int* in_sizes, int n_in,
                              void* d_out, int out_size, void* d_ws, size_t ws_size,
                              hipStream_t stream)
{
    (void)in_sizes; (void)n_in; (void)out_size; (void)ws_size;
    const float* x     = (const float*)d_in[0];
    const float* R     = (const float*)d_in[1];
    const float* fc0_w = (const float*)d_in[2];
    const float* fc0_b = (const float*)d_in[3];
    const float* w1    = (const float*)d_in[4];
    const float* w2    = (const float*)d_in[5];
    const float* w3    = (const float*)d_in[6];
    const float* w4    = (const float*)d_in[7];
    float* out = (float*)d_out;

    // workspace layout (bytes):
    //   J     @ 0           (656, padded to 1024)
    //   Wall  @ 1024        (4,751,360)
    //   Dws   @ 4,752,384   (10,747,904)
    //   U     @ 15,500,288  (104,857,600)
    //   Y     @ 120,357,888 (104,857,600)  -> total 225,215,488
    //   trig aliased onto Y's first 1.31 MB (dead before gemm writes Y)
    char* ws = (char*)d_ws;
    float*          Jws  = (float*)ws;
    __hip_bfloat16* Wall = (__hip_bfloat16*)(ws + 1024);
    float*          Dws  = (float*)(ws + 4752384);
    __hip_bfloat16* U    = (__hip_bfloat16*)(ws + 15500288);
    __hip_bfloat16* Y    = (__hip_bfloat16*)(ws + 120357888);
    float*          trig = (float*)(ws + 120357888);   // alias, see above

    build_J     <<<dim3(4),              dim3(128), 0, stream>>>(Jws);
    prep_w      <<<dim3(4096, 5),        dim3(256), 0, stream>>>(fc0_w, w1, w2, w3, w4, Wall);
    build_trig  <<<dim3(64),             dim3(256), 0, stream>>>(R, trig);
    build_D     <<<dim3(10496),          dim3(256), 0, stream>>>(Jws, trig, Dws);
    rot_gather  <<<dim3(N_ROWS/RG_ROWS), dim3(256), 0, stream>>>(x, Dws, U);
    gemm_bt     <<<dim3(832),            dim3(512), 0, stream>>>(U, Wall, fc0_b, Y);
    ungather_rot<<<dim3(N_ROWS/RG_ROWS), dim3(256), 0, stream>>>(Y, Dws, out);
}